// Round 1
// baseline (616.544 us; speedup 1.0000x reference)
//
#include <hip/hip_runtime.h>
#include <hip/hip_bf16.h>

#define B_  4
#define SQ  4096
#define SKV 4096
#define DM  1024
#define NH  16
#define HD  64
#define CAP 512

typedef __attribute__((ext_vector_type(8))) short    short8;   // 8 bf16 payload (4 VGPRs)
typedef __attribute__((ext_vector_type(8))) __bf16   bf16v8;   // builtin operand type
typedef __attribute__((ext_vector_type(4))) float    f32x4;
typedef __attribute__((ext_vector_type(4))) unsigned short ushort4v;

static __device__ __forceinline__ unsigned short f2bf(float f) {
    unsigned u = __float_as_uint(f);
    u += 0x7FFFu + ((u >> 16) & 1u);           // round-to-nearest-even
    return (unsigned short)(u >> 16);
}

static __device__ __forceinline__ f32x4 mfma_bf16(short8 a, short8 b, f32x4 c) {
    return __builtin_amdgcn_mfma_f32_16x16x32_bf16(
        __builtin_bit_cast(bf16v8, a), __builtin_bit_cast(bf16v8, b), c, 0, 0, 0);
}

#define GLD16(gp, lp)                                                              \
    __builtin_amdgcn_global_load_lds(                                              \
        (__attribute__((address_space(1))) void*)(gp),                             \
        (__attribute__((address_space(3))) void*)(lp), 16, 0, 0)

// ---------------- fp32 -> bf16 bulk convert (grid = n/1024) ----------------
__global__ void __launch_bounds__(256) k_convert(const float* __restrict__ in,
                                                 unsigned short* __restrict__ out) {
    size_t i = (size_t)blockIdx.x * 256 + threadIdx.x;
    float4 f = ((const float4*)in)[i];
    ushort4v o = { f2bf(f.x), f2bf(f.y), f2bf(f.z), f2bf(f.w) };
    ((ushort4v*)out)[i] = o;
}

// ---------------- RoPE table: tab[pos*64+i], i<32 -> sin, i>=32 -> cos ----------------
__global__ void __launch_bounds__(256) k_rope(float* __restrict__ tab) {
    int g = blockIdx.x * 256 + threadIdx.x;   // 0..262143
    int pos = g >> 6, i = g & 63, j = i & 31;
    float freq = expf(-(float)j * (logf(10000.0f) / 31.0f));
    float ang  = (float)pos * freq;
    tab[g] = (i < 32) ? sinf(ang) : cosf(ang);
}

// ---------------- router scores: one wave per row ----------------
__global__ void __launch_bounds__(256) k_router(const float* __restrict__ q,
                                                const float* __restrict__ wv,
                                                float* __restrict__ rw) {
    int row  = blockIdx.x * 4 + (threadIdx.x >> 6);
    int lane = threadIdx.x & 63;
    const float* p  = q  + (size_t)row * DM + lane * 16;
    const float* wp = wv + lane * 16;
    float s = 0.f;
#pragma unroll
    for (int j = 0; j < 4; j++) {
        float4 a = ((const float4*)p)[j];
        float4 b = ((const float4*)wp)[j];
        s += a.x * b.x + a.y * b.y + a.z * b.z + a.w * b.w;
    }
#pragma unroll
    for (int m = 32; m > 0; m >>= 1) s += __shfl_xor(s, m, 64);
    if (lane == 0) rw[row] = s;
}

// ---------------- top-512 of 4096 via bitonic sort on (value desc, idx asc) ----------------
__global__ void __launch_bounds__(1024) k_topk(const float* __restrict__ rw,
                                               int* __restrict__ sel,
                                               float* __restrict__ selw) {
    __shared__ unsigned long long keys[4096];
    int b = blockIdx.x, t = threadIdx.x;
    for (int i = t; i < 4096; i += 1024) {
        float v = rw[b * 4096 + i];
        unsigned u = __float_as_uint(v);
        u = (u & 0x80000000u) ? ~u : (u | 0x80000000u);    // monotonic ascending transform
        keys[i] = ((unsigned long long)(~u) << 32) | (unsigned)i;  // ascending key = value desc, idx asc
    }
    __syncthreads();
    for (int k = 2; k <= 4096; k <<= 1)
        for (int j = k >> 1; j > 0; j >>= 1) {
            for (int i = t; i < 4096; i += 1024) {
                int ixj = i ^ j;
                if (ixj > i) {
                    bool up = ((i & k) == 0);
                    unsigned long long a = keys[i], c = keys[ixj];
                    if ((a > c) == up) { keys[i] = c; keys[ixj] = a; }
                }
            }
            __syncthreads();
        }
    for (int i = t; i < 512; i += 1024) {
        unsigned idx = (unsigned)(keys[i] & 0xFFFFFFFFu);
        sel[b * 512 + i]  = (int)idx;
        selw[b * 512 + i] = rw[b * 4096 + idx];
    }
}

// ---------------- gather selected query rows -> bf16 ----------------
__global__ void __launch_bounds__(256) k_gather(const float* __restrict__ q,
                                                const int* __restrict__ sel,
                                                unsigned short* __restrict__ out) {
    int row = blockIdx.x;                  // b*512 + c
    int b = row >> 9;
    int s = sel[row];
    const float4* src = (const float4*)(q + ((size_t)b * SQ + s) * DM);
    ushort4v* dst = (ushort4v*)(out + (size_t)row * DM);
    float4 f = src[threadIdx.x];
    ushort4v o = { f2bf(f.x), f2bf(f.y), f2bf(f.z), f2bf(f.w) };
    dst[threadIdx.x] = o;
}

// ---------------- 128x128x32 MFMA GEMM, C = A * Bw^T, with fused epilogues ----------------
// MODE 0: kv projection -> k_attn (B,H,S,d) with RoPE, v_attn transposed (B,H,d,S)
// MODE 1: q projection  -> q_attn (B,H,C,d) with RoPE(sel pos) * 0.125
// MODE 2: out projection -> scatter fp32 rows * selw into out
template <int MODE>
__global__ void __launch_bounds__(256) k_gemm(
    const unsigned short* __restrict__ A,
    const unsigned short* __restrict__ Bw,
    int M, int N, int K,
    const float* __restrict__ rope_tab,
    const int* __restrict__ sel,
    const float* __restrict__ selw,
    unsigned short* __restrict__ ok,
    unsigned short* __restrict__ ov,
    unsigned short* __restrict__ obf,
    float* __restrict__ of) {
    __shared__ unsigned short lA[128 * 32];
    __shared__ unsigned short lB[128 * 32];
    const int tid = threadIdx.x;
    const int w = tid >> 6, lane = tid & 63, quad = lane >> 4, l16 = lane & 15;
    const int wr = w >> 1, wc = w & 1;
    const int mBase = blockIdx.y * 128, nBase = blockIdx.x * 128;

    f32x4 acc[4][4] = {};

    for (int k0 = 0; k0 < K; k0 += 32) {
#pragma unroll
        for (int is = 0; is < 2; is++) {
            int f = is * 4096 + tid * 16;           // byte offset in 8KB tile
            int row = f >> 6, inner = f & 63;       // 64B per row (32 bf16)
            const char* ga = (const char*)A  + ((size_t)(mBase + row) * K + k0) * 2 + inner;
            const char* gb = (const char*)Bw + ((size_t)(nBase + row) * K + k0) * 2 + inner;
            GLD16(ga, (char*)lA + f);
            GLD16(gb, (char*)lB + f);
        }
        __syncthreads();
        short8 af[4], bfr[4];
#pragma unroll
        for (int t = 0; t < 4; t++) {
            af[t]  = *(const short8*)&lA[(wr * 64 + t * 16 + l16) * 32 + quad * 8];
            bfr[t] = *(const short8*)&lB[(wc * 64 + t * 16 + l16) * 32 + quad * 8];
        }
#pragma unroll
        for (int tm = 0; tm < 4; tm++)
#pragma unroll
            for (int tn = 0; tn < 4; tn++)
                acc[tm][tn] = mfma_bf16(af[tm], bfr[tn], acc[tm][tn]);
        __syncthreads();
    }

#pragma unroll
    for (int tm = 0; tm < 4; tm++) {
#pragma unroll
        for (int tn = 0; tn < 4; tn++) {
#pragma unroll
            for (int r = 0; r < 4; r++) {
                int m = mBase + wr * 64 + tm * 16 + quad * 4 + r;
                int n = nBase + wc * 64 + tn * 16 + l16;
                float v = acc[tm][tn][r];
                if constexpr (MODE == 0) {
                    int b = m >> 12, s = m & 4095;
                    if (n < 1024) {
                        int h = n >> 6, i = n & 63;
                        v *= rope_tab[(s << 6) | i];
                        ok[(((size_t)(b * NH + h) * SKV) + s) * HD + i] = f2bf(v);
                    } else {
                        int e = n - 1024, h = e >> 6, i = e & 63;
                        ov[(((size_t)(b * NH + h) * HD) + i) * SKV + s] = f2bf(v);
                    }
                } else if constexpr (MODE == 1) {
                    int b = m >> 9, c = m & 511;
                    int h = n >> 6, i = n & 63;
                    float rp = rope_tab[(sel[m] << 6) | i];
                    obf[(((size_t)(b * NH + h) * CAP) + c) * HD + i] = f2bf(v * rp * 0.125f);
                } else {
                    int b = m >> 9;
                    int s = sel[m];
                    of[(((size_t)b * SQ) + s) * DM + n] = v * selw[m];
                }
            }
        }
    }
}

// ---------------- flash attention: 64 q-rows/block, online softmax ----------------
__global__ void __launch_bounds__(256) k_attention(
    const unsigned short* __restrict__ Q,    // (B,H,C,d)
    const unsigned short* __restrict__ Kg,   // (B,H,S,d)
    const unsigned short* __restrict__ Vt,   // (B,H,d,S)
    unsigned short* __restrict__ O) {        // (B,C,H*d)
    __shared__ unsigned short lK[64 * 72];       // [s][i], padded
    __shared__ unsigned short lV[64 * 72];       // [i][s], padded
    __shared__ unsigned short lP[4][16 * 72];    // per-wave P round-trip
    const int bh = blockIdx.y, tile = blockIdx.x;
    const int tid = threadIdx.x, w = tid >> 6, lane = tid & 63;
    const int quad = lane >> 4, l16 = lane & 15;
    const int qrow = tile * 64 + w * 16;

    const unsigned short* qp = Q + ((size_t)bh * CAP + qrow + l16) * HD + quad * 8;
    short8 qf0 = *(const short8*)qp;
    short8 qf1 = *(const short8*)(qp + 32);

    const unsigned short* kb = Kg + (size_t)bh * SKV * HD;
    const unsigned short* vb = Vt + (size_t)bh * HD * SKV;

    f32x4 o[4] = {};
    float mrow[4] = { -1e30f, -1e30f, -1e30f, -1e30f };
    float lrow[4] = { 0.f, 0.f, 0.f, 0.f };

    const int sr = tid >> 2, sp = tid & 3;

    for (int s0 = 0; s0 < SKV; s0 += 64) {
        {   // stage K (s-major) and Vt (d-major), 32B per thread each
            const short8* srck = (const short8*)(kb + (size_t)(s0 + sr) * HD + sp * 16);
            *(short8*)&lK[sr * 72 + sp * 16]     = srck[0];
            *(short8*)&lK[sr * 72 + sp * 16 + 8] = srck[1];
            const short8* srcv = (const short8*)(vb + (size_t)sr * SKV + s0 + sp * 16);
            *(short8*)&lV[sr * 72 + sp * 16]     = srcv[0];
            *(short8*)&lV[sr * 72 + sp * 16 + 8] = srcv[1];
        }
        __syncthreads();
        // QK^T: S[c][s], c rows of this wave
        f32x4 sc[4] = {};
#pragma unroll
        for (int tn = 0; tn < 4; tn++) {
            short8 kf0 = *(const short8*)&lK[(tn * 16 + l16) * 72 + quad * 8];
            short8 kf1 = *(const short8*)&lK[(tn * 16 + l16) * 72 + 32 + quad * 8];
            sc[tn] = mfma_bf16(qf0, kf0, sc[tn]);
            sc[tn] = mfma_bf16(qf1, kf1, sc[tn]);
        }
        // online softmax (rows owned: quad*4+r; cols: l16 across 4 subtiles)
#pragma unroll
        for (int r = 0; r < 4; r++) {
            float t = fmaxf(fmaxf(sc[0][r], sc[1][r]), fmaxf(sc[2][r], sc[3][r]));
            t = fmaxf(t, __shfl_xor(t, 1, 64));
            t = fmaxf(t, __shfl_xor(t, 2, 64));
            t = fmaxf(t, __shfl_xor(t, 4, 64));
            t = fmaxf(t, __shfl_xor(t, 8, 64));
            float mn = fmaxf(mrow[r], t);
            float al = __expf(mrow[r] - mn);
            mrow[r] = mn;
            lrow[r] *= al;
#pragma unroll
            for (int t2 = 0; t2 < 4; t2++) o[t2][r] *= al;
            float ls = 0.f;
#pragma unroll
            for (int tn = 0; tn < 4; tn++) {
                float pv = __expf(sc[tn][r] - mn);
                sc[tn][r] = pv;
                ls += pv;
            }
            ls += __shfl_xor(ls, 1, 64);
            ls += __shfl_xor(ls, 2, 64);
            ls += __shfl_xor(ls, 4, 64);
            ls += __shfl_xor(ls, 8, 64);
            lrow[r] += ls;
#pragma unroll
            for (int tn = 0; tn < 4; tn++)
                lP[w][(quad * 4 + r) * 72 + tn * 16 + l16] = f2bf(sc[tn][r]);
        }
        // PV: O[c][i] += P * V
#pragma unroll
        for (int kc = 0; kc < 2; kc++) {
            short8 pf = *(const short8*)&lP[w][l16 * 72 + kc * 32 + quad * 8];
#pragma unroll
            for (int tn = 0; tn < 4; tn++) {
                short8 vf = *(const short8*)&lV[(tn * 16 + l16) * 72 + kc * 32 + quad * 8];
                o[tn] = mfma_bf16(pf, vf, o[tn]);
            }
        }
        __syncthreads();
    }
    const int b = bh >> 4, h = bh & 15;
#pragma unroll
    for (int r = 0; r < 4; r++) {
        float inv = 1.0f / lrow[r];
        int c = qrow + quad * 4 + r;
#pragma unroll
        for (int tn = 0; tn < 4; tn++)
            O[((size_t)(b * CAP + c)) * DM + h * HD + tn * 16 + l16] = f2bf(o[tn][r] * inv);
    }
}

extern "C" void kernel_launch(void* const* d_in, const int* in_sizes, int n_in,
                              void* d_out, int out_size, void* d_ws, size_t ws_size,
                              hipStream_t stream) {
    const float* query    = (const float*)d_in[0];
    const float* value    = (const float*)d_in[1];
    const float* router_w = (const float*)d_in[2];
    const float* q_w      = (const float*)d_in[3];
    const float* kv_w     = (const float*)d_in[4];
    const float* out_w    = (const float*)d_in[5];
    float* out = (float*)d_out;

    char* p = (char*)d_ws;
    unsigned short* value_bf = (unsigned short*)p; p += (size_t)B_ * SKV * DM * 2;  // 33.5MB
    unsigned short* kvw_bf   = (unsigned short*)p; p += (size_t)2 * DM * DM * 2;    // 4MB
    unsigned short* qw_bf    = (unsigned short*)p; p += (size_t)DM * DM * 2;        // 2MB
    unsigned short* ow_bf    = (unsigned short*)p; p += (size_t)DM * DM * 2;        // 2MB
    unsigned short* res_bf   = (unsigned short*)p; p += (size_t)B_ * CAP * DM * 2;  // 4MB
    unsigned short* q_attn   = (unsigned short*)p; p += (size_t)B_ * CAP * DM * 2;  // 4MB
    unsigned short* kbuf     = (unsigned short*)p; p += (size_t)B_ * SKV * DM * 2;  // 33.5MB
    unsigned short* vbuf     = (unsigned short*)p; p += (size_t)B_ * SKV * DM * 2;  // 33.5MB
    unsigned short* att_bf   = (unsigned short*)p; p += (size_t)B_ * CAP * DM * 2;  // 4MB
    float* rope_tab = (float*)p; p += (size_t)SKV * HD * 4;                          // 1MB
    float* rw       = (float*)p; p += (size_t)B_ * SQ * 4;
    int*   sel      = (int*)p;   p += (size_t)B_ * CAP * 4;
    float* selw     = (float*)p; p += (size_t)B_ * CAP * 4;

    hipMemsetAsync(d_out, 0, (size_t)out_size * sizeof(float), stream);

    k_convert<<<B_ * SKV * DM / 1024, 256, 0, stream>>>(value, value_bf);
    k_convert<<<2 * DM * DM / 1024, 256, 0, stream>>>(kv_w, kvw_bf);
    k_convert<<<DM * DM / 1024, 256, 0, stream>>>(q_w, qw_bf);
    k_convert<<<DM * DM / 1024, 256, 0, stream>>>(out_w, ow_bf);
    k_rope<<<SKV * HD / 256, 256, 0, stream>>>(rope_tab);
    k_router<<<B_ * SQ / 4, 256, 0, stream>>>(query, router_w, rw);
    k_topk<<<B_, 1024, 0, stream>>>(rw, sel, selw);
    k_gather<<<B_ * CAP, 256, 0, stream>>>(query, sel, res_bf);

    // kv projection + RoPE(k) + layout
    k_gemm<0><<<dim3(2 * DM / 128, B_ * SKV / 128), 256, 0, stream>>>(
        value_bf, kvw_bf, B_ * SKV, 2 * DM, DM, rope_tab, nullptr, nullptr,
        kbuf, vbuf, nullptr, nullptr);
    // q projection + RoPE(sel) + 1/sqrt(d)
    k_gemm<1><<<dim3(DM / 128, B_ * CAP / 128), 256, 0, stream>>>(
        res_bf, qw_bf, B_ * CAP, DM, DM, rope_tab, sel, nullptr,
        nullptr, nullptr, q_attn, nullptr);

    k_attention<<<dim3(CAP / 64, B_ * NH), 256, 0, stream>>>(q_attn, kbuf, vbuf, att_bf);

    // out projection + topw scale + scatter
    k_gemm<2><<<dim3(DM / 128, B_ * CAP / 128), 256, 0, stream>>>(
        att_bf, ow_bf, B_ * CAP, DM, DM, nullptr, sel, selw,
        nullptr, nullptr, nullptr, out);
}

// Round 2
// 523.781 us; speedup vs baseline: 1.1771x; 1.1771x over previous
//
#include <hip/hip_runtime.h>
#include <hip/hip_bf16.h>

#define B_  4
#define SQ  4096
#define SKV 4096
#define DM  1024
#define NH  16
#define HD  64
#define CAP 512

#define ASPLIT 4
#define KVPER  (SKV / ASPLIT)
#define AITERS (KVPER / 64)

typedef __attribute__((ext_vector_type(8))) short    short8;   // 8 bf16 payload (4 VGPRs)
typedef __attribute__((ext_vector_type(8))) __bf16   bf16v8;   // builtin operand type
typedef __attribute__((ext_vector_type(4))) float    f32x4;
typedef __attribute__((ext_vector_type(4))) unsigned short ushort4v;

static __device__ __forceinline__ unsigned short f2bf(float f) {
    unsigned u = __float_as_uint(f);
    u += 0x7FFFu + ((u >> 16) & 1u);           // round-to-nearest-even
    return (unsigned short)(u >> 16);
}

static __device__ __forceinline__ f32x4 mfma_bf16(short8 a, short8 b, f32x4 c) {
    return __builtin_amdgcn_mfma_f32_16x16x32_bf16(
        __builtin_bit_cast(bf16v8, a), __builtin_bit_cast(bf16v8, b), c, 0, 0, 0);
}

#define GLD16(gp, lp)                                                              \
    __builtin_amdgcn_global_load_lds(                                              \
        (__attribute__((address_space(1))) void*)(gp),                             \
        (__attribute__((address_space(3))) void*)(lp), 16, 0, 0)

// ---------------- fp32 -> bf16 bulk convert (grid = n/1024) ----------------
__global__ void __launch_bounds__(256) k_convert(const float* __restrict__ in,
                                                 unsigned short* __restrict__ out) {
    size_t i = (size_t)blockIdx.x * 256 + threadIdx.x;
    float4 f = ((const float4*)in)[i];
    ushort4v o = { f2bf(f.x), f2bf(f.y), f2bf(f.z), f2bf(f.w) };
    ((ushort4v*)out)[i] = o;
}

// ---------------- RoPE table: tab[pos*64+i], i<32 -> sin, i>=32 -> cos ----------------
__global__ void __launch_bounds__(256) k_rope(float* __restrict__ tab) {
    int g = blockIdx.x * 256 + threadIdx.x;   // 0..262143
    int pos = g >> 6, i = g & 63, j = i & 31;
    float freq = expf(-(float)j * (logf(10000.0f) / 31.0f));
    float ang  = (float)pos * freq;
    tab[g] = (i < 32) ? sinf(ang) : cosf(ang);
}

// ---------------- router scores: one wave per row ----------------
__global__ void __launch_bounds__(256) k_router(const float* __restrict__ q,
                                                const float* __restrict__ wv,
                                                float* __restrict__ rw) {
    int row  = blockIdx.x * 4 + (threadIdx.x >> 6);
    int lane = threadIdx.x & 63;
    const float* p  = q  + (size_t)row * DM + lane * 16;
    const float* wp = wv + lane * 16;
    float s = 0.f;
#pragma unroll
    for (int j = 0; j < 4; j++) {
        float4 a = ((const float4*)p)[j];
        float4 b = ((const float4*)wp)[j];
        s += a.x * b.x + a.y * b.y + a.z * b.z + a.w * b.w;
    }
#pragma unroll
    for (int m = 32; m > 0; m >>= 1) s += __shfl_xor(s, m, 64);
    if (lane == 0) rw[row] = s;
}

// ---------------- top-512 of 4096 via bitonic sort on (value desc, idx asc) ----------------
__global__ void __launch_bounds__(1024) k_topk(const float* __restrict__ rw,
                                               int* __restrict__ sel,
                                               float* __restrict__ selw) {
    __shared__ unsigned long long keys[4096];
    int b = blockIdx.x, t = threadIdx.x;
    for (int i = t; i < 4096; i += 1024) {
        float v = rw[b * 4096 + i];
        unsigned u = __float_as_uint(v);
        u = (u & 0x80000000u) ? ~u : (u | 0x80000000u);    // monotonic ascending transform
        keys[i] = ((unsigned long long)(~u) << 32) | (unsigned)i;  // ascending key = value desc, idx asc
    }
    __syncthreads();
    for (int k = 2; k <= 4096; k <<= 1)
        for (int j = k >> 1; j > 0; j >>= 1) {
            for (int i = t; i < 4096; i += 1024) {
                int ixj = i ^ j;
                if (ixj > i) {
                    bool up = ((i & k) == 0);
                    unsigned long long a = keys[i], c = keys[ixj];
                    if ((a > c) == up) { keys[i] = c; keys[ixj] = a; }
                }
            }
            __syncthreads();
        }
    for (int i = t; i < 512; i += 1024) {
        unsigned idx = (unsigned)(keys[i] & 0xFFFFFFFFu);
        sel[b * 512 + i]  = (int)idx;
        selw[b * 512 + i] = rw[b * 4096 + idx];
    }
}

// ---------------- gather selected query rows -> bf16 ----------------
__global__ void __launch_bounds__(256) k_gather(const float* __restrict__ q,
                                                const int* __restrict__ sel,
                                                unsigned short* __restrict__ out) {
    int row = blockIdx.x;                  // b*512 + c
    int b = row >> 9;
    int s = sel[row];
    const float4* src = (const float4*)(q + ((size_t)b * SQ + s) * DM);
    ushort4v* dst = (ushort4v*)(out + (size_t)row * DM);
    float4 f = src[threadIdx.x];
    ushort4v o = { f2bf(f.x), f2bf(f.y), f2bf(f.z), f2bf(f.w) };
    dst[threadIdx.x] = o;
}

// ---------------- 128x128x32 MFMA GEMM, C = A * Bw^T, with fused epilogues ----------------
// MODE 0: kv projection -> k_attn (B,H,S,d) with RoPE, v_attn transposed (B,H,d,S)
// MODE 1: q projection  -> q_attn (B,H,C,d) with RoPE(sel pos) * 0.125
// MODE 2: out projection -> scatter fp32 rows * selw into out
template <int MODE>
__global__ void __launch_bounds__(256) k_gemm(
    const unsigned short* __restrict__ A,
    const unsigned short* __restrict__ Bw,
    int M, int N, int K,
    const float* __restrict__ rope_tab,
    const int* __restrict__ sel,
    const float* __restrict__ selw,
    unsigned short* __restrict__ ok,
    unsigned short* __restrict__ ov,
    unsigned short* __restrict__ obf,
    float* __restrict__ of) {
    __shared__ unsigned short lA[128 * 32];
    __shared__ unsigned short lB[128 * 32];
    const int tid = threadIdx.x;
    const int w = tid >> 6, lane = tid & 63, quad = lane >> 4, l16 = lane & 15;
    const int wr = w >> 1, wc = w & 1;
    const int mBase = blockIdx.y * 128, nBase = blockIdx.x * 128;

    f32x4 acc[4][4] = {};

    for (int k0 = 0; k0 < K; k0 += 32) {
#pragma unroll
        for (int is = 0; is < 2; is++) {
            int f = is * 4096 + tid * 16;           // byte offset in 8KB tile
            int row = f >> 6, inner = f & 63;       // 64B per row (32 bf16)
            const char* ga = (const char*)A  + ((size_t)(mBase + row) * K + k0) * 2 + inner;
            const char* gb = (const char*)Bw + ((size_t)(nBase + row) * K + k0) * 2 + inner;
            GLD16(ga, (char*)lA + f);
            GLD16(gb, (char*)lB + f);
        }
        __syncthreads();
        short8 af[4], bfr[4];
#pragma unroll
        for (int t = 0; t < 4; t++) {
            af[t]  = *(const short8*)&lA[(wr * 64 + t * 16 + l16) * 32 + quad * 8];
            bfr[t] = *(const short8*)&lB[(wc * 64 + t * 16 + l16) * 32 + quad * 8];
        }
#pragma unroll
        for (int tm = 0; tm < 4; tm++)
#pragma unroll
            for (int tn = 0; tn < 4; tn++)
                acc[tm][tn] = mfma_bf16(af[tm], bfr[tn], acc[tm][tn]);
        __syncthreads();
    }

#pragma unroll
    for (int tm = 0; tm < 4; tm++) {
#pragma unroll
        for (int tn = 0; tn < 4; tn++) {
#pragma unroll
            for (int r = 0; r < 4; r++) {
                int m = mBase + wr * 64 + tm * 16 + quad * 4 + r;
                int n = nBase + wc * 64 + tn * 16 + l16;
                float v = acc[tm][tn][r];
                if constexpr (MODE == 0) {
                    int b = m >> 12, s = m & 4095;
                    if (n < 1024) {
                        int h = n >> 6, i = n & 63;
                        v *= rope_tab[(s << 6) | i];
                        ok[(((size_t)(b * NH + h) * SKV) + s) * HD + i] = f2bf(v);
                    } else {
                        int e = n - 1024, h = e >> 6, i = e & 63;
                        ov[(((size_t)(b * NH + h) * HD) + i) * SKV + s] = f2bf(v);
                    }
                } else if constexpr (MODE == 1) {
                    int b = m >> 9, c = m & 511;
                    int h = n >> 6, i = n & 63;
                    float rp = rope_tab[(sel[m] << 6) | i];
                    obf[(((size_t)(b * NH + h) * CAP) + c) * HD + i] = f2bf(v * rp * 0.125f);
                } else {
                    int b = m >> 9;
                    int s = sel[m];
                    of[(((size_t)b * SQ) + s) * DM + n] = v * selw[m];
                }
            }
        }
    }
}

// ---------------- flash attention (KV-split, no-max softmax, unnormalized partials) ------
// grid (CAP/128, B*NH, ASPLIT), block 256. Each wave: 32 q-rows. Partials fp32.
__global__ void __launch_bounds__(256) k_attention(
    const unsigned short* __restrict__ Q,    // (B,H,C,d)
    const unsigned short* __restrict__ Kg,   // (B,H,S,d)
    const unsigned short* __restrict__ Vt,   // (B,H,d,S)
    float* __restrict__ Opart,               // (ASPLIT,B*H,C,d) unnormalized
    float* __restrict__ Lpart) {             // (ASPLIT,B*H,C)
    __shared__ unsigned short lK[64 * 72];       // [s][i], padded
    __shared__ unsigned short lV[64 * 72];       // [i][s], padded
    __shared__ unsigned short lP[4][32 * 72];    // per-wave P round-trip
    const int bh = blockIdx.y, z = blockIdx.z;
    const int tid = threadIdx.x, w = tid >> 6, lane = tid & 63;
    const int quad = lane >> 4, l16 = lane & 15;
    const int qb = blockIdx.x * 128 + w * 32;        // wave's q base (32 rows)
    const int base = z * KVPER;

    // Q fragments: qf[rt][kc], rows qb + rt*16 + l16, k = kc*32 + quad*8
    short8 qf[2][2];
#pragma unroll
    for (int rt = 0; rt < 2; rt++) {
        const unsigned short* qp = Q + ((size_t)bh * CAP + qb + rt * 16 + l16) * HD + quad * 8;
        qf[rt][0] = *(const short8*)qp;
        qf[rt][1] = *(const short8*)(qp + 32);
    }

    const unsigned short* kb = Kg + (size_t)bh * SKV * HD;
    const unsigned short* vb = Vt + (size_t)bh * HD * SKV;
    const int sr = tid >> 2, sp = tid & 3;           // staging: row, 16-half chunk

    f32x4 o[2][4] = {};
    f32x4 lsum[2] = {};
    short8 ones = (short8)0x3F80;                    // bf16 1.0 splat

    // prefetch tile 0
    short8 rk0, rk1, rv0, rv1;
    {
        const short8* srck = (const short8*)(kb + (size_t)(base + sr) * HD + sp * 16);
        rk0 = srck[0]; rk1 = srck[1];
        const short8* srcv = (const short8*)(vb + (size_t)sr * SKV + base + sp * 16);
        rv0 = srcv[0]; rv1 = srcv[1];
    }

    unsigned short* lPw = &lP[w][0];

    for (int it = 0; it < AITERS; it++) {
        __syncthreads();                             // all waves done reading prev tile
        *(short8*)&lK[sr * 72 + sp * 16]     = rk0;
        *(short8*)&lK[sr * 72 + sp * 16 + 8] = rk1;
        *(short8*)&lV[sr * 72 + sp * 16]     = rv0;
        *(short8*)&lV[sr * 72 + sp * 16 + 8] = rv1;
        if (it + 1 < AITERS) {                       // prefetch next tile (hides HBM latency)
            int s0 = base + (it + 1) * 64;
            const short8* srck = (const short8*)(kb + (size_t)(s0 + sr) * HD + sp * 16);
            rk0 = srck[0]; rk1 = srck[1];
            const short8* srcv = (const short8*)(vb + (size_t)sr * SKV + s0 + sp * 16);
            rv0 = srcv[0]; rv1 = srcv[1];
        }
        __syncthreads();                             // tile visible

        // QK^T
        f32x4 sc[2][4] = {};
#pragma unroll
        for (int tn = 0; tn < 4; tn++) {
            short8 kf0 = *(const short8*)&lK[(tn * 16 + l16) * 72 + quad * 8];
            short8 kf1 = *(const short8*)&lK[(tn * 16 + l16) * 72 + 32 + quad * 8];
#pragma unroll
            for (int rt = 0; rt < 2; rt++) {
                sc[rt][tn] = mfma_bf16(qf[rt][0], kf0, sc[rt][tn]);
                sc[rt][tn] = mfma_bf16(qf[rt][1], kf1, sc[rt][tn]);
            }
        }
        // exp (no max subtraction; scores bounded ~|3|, clamp 60 as insurance)
#pragma unroll
        for (int rt = 0; rt < 2; rt++)
#pragma unroll
            for (int tn = 0; tn < 4; tn++)
#pragma unroll
                for (int r = 0; r < 4; r++)
                    lPw[(rt * 16 + quad * 4 + r) * 72 + tn * 16 + l16] =
                        f2bf(__expf(fminf(sc[rt][tn][r], 60.f)));
        // PV + row-sum via ones-MFMA (wave-private lP: no barrier needed)
#pragma unroll
        for (int kc = 0; kc < 2; kc++) {
            short8 pf0 = *(const short8*)&lPw[(l16) * 72 + kc * 32 + quad * 8];
            short8 pf1 = *(const short8*)&lPw[(16 + l16) * 72 + kc * 32 + quad * 8];
            lsum[0] = mfma_bf16(pf0, ones, lsum[0]);
            lsum[1] = mfma_bf16(pf1, ones, lsum[1]);
#pragma unroll
            for (int tn = 0; tn < 4; tn++) {
                short8 vf = *(const short8*)&lV[(tn * 16 + l16) * 72 + kc * 32 + quad * 8];
                o[0][tn] = mfma_bf16(pf0, vf, o[0][tn]);
                o[1][tn] = mfma_bf16(pf1, vf, o[1][tn]);
            }
        }
    }

    // write unnormalized partials
    float* Ob = Opart + (((size_t)(z * 64 + bh)) * CAP + qb) * HD;
#pragma unroll
    for (int rt = 0; rt < 2; rt++)
#pragma unroll
        for (int tn = 0; tn < 4; tn++)
#pragma unroll
            for (int r = 0; r < 4; r++)
                Ob[(size_t)(rt * 16 + quad * 4 + r) * HD + tn * 16 + l16] = o[rt][tn][r];
    if (l16 == 0) {
#pragma unroll
        for (int rt = 0; rt < 2; rt++)
#pragma unroll
            for (int r = 0; r < 4; r++)
                Lpart[((size_t)(z * 64 + bh)) * CAP + qb + rt * 16 + quad * 4 + r] = lsum[rt][r];
    }
}

// ---------------- combine split partials -> att_bf (B,C,H*d) ----------------
__global__ void __launch_bounds__(256) k_combine(
    const float* __restrict__ Opart, const float* __restrict__ Lpart,
    unsigned short* __restrict__ att) {
    int g = blockIdx.x * 256 + threadIdx.x;          // (b,c,h,dd) flattened = output index
    int dall = g & 1023, c = (g >> 10) & 511, b = g >> 19;
    int h = dall >> 6, dd = dall & 63;
    int bh = b * NH + h;
    float os = 0.f, ls = 0.f;
#pragma unroll
    for (int p = 0; p < ASPLIT; p++) {
        os += Opart[(((size_t)(p * 64 + bh)) * CAP + c) * HD + dd];
        ls += Lpart[((size_t)(p * 64 + bh)) * CAP + c];
    }
    att[g] = f2bf(os / ls);
}

extern "C" void kernel_launch(void* const* d_in, const int* in_sizes, int n_in,
                              void* d_out, int out_size, void* d_ws, size_t ws_size,
                              hipStream_t stream) {
    const float* query    = (const float*)d_in[0];
    const float* value    = (const float*)d_in[1];
    const float* router_w = (const float*)d_in[2];
    const float* q_w      = (const float*)d_in[3];
    const float* kv_w     = (const float*)d_in[4];
    const float* out_w    = (const float*)d_in[5];
    float* out = (float*)d_out;

    char* p = (char*)d_ws;
    unsigned short* value_bf = (unsigned short*)p; p += (size_t)B_ * SKV * DM * 2;  // 33.5MB
    unsigned short* kvw_bf   = (unsigned short*)p; p += (size_t)2 * DM * DM * 2;    // 4MB
    unsigned short* qw_bf    = (unsigned short*)p; p += (size_t)DM * DM * 2;        // 2MB
    unsigned short* ow_bf    = (unsigned short*)p; p += (size_t)DM * DM * 2;        // 2MB
    unsigned short* res_bf   = (unsigned short*)p; p += (size_t)B_ * CAP * DM * 2;  // 4MB
    unsigned short* q_attn   = (unsigned short*)p; p += (size_t)B_ * CAP * DM * 2;  // 4MB
    unsigned short* kbuf     = (unsigned short*)p; p += (size_t)B_ * SKV * DM * 2;  // 33.5MB
    unsigned short* vbuf     = (unsigned short*)p; p += (size_t)B_ * SKV * DM * 2;  // 33.5MB
    unsigned short* att_bf   = (unsigned short*)p; p += (size_t)B_ * CAP * DM * 2;  // 4MB
    float* rope_tab = (float*)p; p += (size_t)SKV * HD * 4;                          // 1MB
    float* rw       = (float*)p; p += (size_t)B_ * SQ * 4;
    int*   sel      = (int*)p;   p += (size_t)B_ * CAP * 4;
    float* selw     = (float*)p; p += (size_t)B_ * CAP * 4;
    // attention partials alias buffers that are dead by the time attention runs:
    // value_bf (32MB needed) consumed by gemm<0>; res_bf (512KB needed) consumed by gemm<1>.
    float* Opart = (float*)value_bf;   // ASPLIT*64*CAP*HD*4 = 32MB <= 33.5MB
    float* Lpart = (float*)res_bf;     // ASPLIT*64*CAP*4 = 512KB <= 4MB

    hipMemsetAsync(d_out, 0, (size_t)out_size * sizeof(float), stream);

    k_convert<<<B_ * SKV * DM / 1024, 256, 0, stream>>>(value, value_bf);
    k_convert<<<2 * DM * DM / 1024, 256, 0, stream>>>(kv_w, kvw_bf);
    k_convert<<<DM * DM / 1024, 256, 0, stream>>>(q_w, qw_bf);
    k_convert<<<DM * DM / 1024, 256, 0, stream>>>(out_w, ow_bf);
    k_rope<<<SKV * HD / 256, 256, 0, stream>>>(rope_tab);
    k_router<<<B_ * SQ / 4, 256, 0, stream>>>(query, router_w, rw);
    k_topk<<<B_, 1024, 0, stream>>>(rw, sel, selw);
    k_gather<<<B_ * CAP, 256, 0, stream>>>(query, sel, res_bf);

    // kv projection + RoPE(k) + layout
    k_gemm<0><<<dim3(2 * DM / 128, B_ * SKV / 128), 256, 0, stream>>>(
        value_bf, kvw_bf, B_ * SKV, 2 * DM, DM, rope_tab, nullptr, nullptr,
        kbuf, vbuf, nullptr, nullptr);
    // q projection + RoPE(sel) + 1/sqrt(d)
    k_gemm<1><<<dim3(DM / 128, B_ * CAP / 128), 256, 0, stream>>>(
        res_bf, qw_bf, B_ * CAP, DM, DM, rope_tab, sel, nullptr,
        nullptr, nullptr, q_attn, nullptr);

    k_attention<<<dim3(CAP / 128, B_ * NH, ASPLIT), 256, 0, stream>>>(
        q_attn, kbuf, vbuf, Opart, Lpart);
    k_combine<<<B_ * CAP * DM / 256, 256, 0, stream>>>(Opart, Lpart, att_bf);

    // out projection + topw scale + scatter
    k_gemm<2><<<dim3(DM / 128, B_ * CAP / 128), 256, 0, stream>>>(
        att_bf, ow_bf, B_ * CAP, DM, DM, nullptr, sel, selw,
        nullptr, nullptr, nullptr, out);
}

// Round 3
// 523.706 us; speedup vs baseline: 1.1773x; 1.0001x over previous
//
#include <hip/hip_runtime.h>
#include <hip/hip_bf16.h>

#define B_  4
#define SQ  4096
#define SKV 4096
#define DM  1024
#define NH  16
#define HD  64
#define CAP 512

#define ASPLIT 4
#define KVPER  (SKV / ASPLIT)
#define AITERS (KVPER / 64)

typedef __attribute__((ext_vector_type(8))) short    short8;   // 8 bf16 payload (4 VGPRs)
typedef __attribute__((ext_vector_type(8))) __bf16   bf16v8;   // builtin operand type
typedef __attribute__((ext_vector_type(4))) float    f32x4;
typedef __attribute__((ext_vector_type(4))) unsigned short ushort4v;

static __device__ __forceinline__ unsigned short f2bf(float f) {
    unsigned u = __float_as_uint(f);
    u += 0x7FFFu + ((u >> 16) & 1u);           // round-to-nearest-even
    return (unsigned short)(u >> 16);
}

static __device__ __forceinline__ f32x4 mfma_bf16(short8 a, short8 b, f32x4 c) {
    return __builtin_amdgcn_mfma_f32_16x16x32_bf16(
        __builtin_bit_cast(bf16v8, a), __builtin_bit_cast(bf16v8, b), c, 0, 0, 0);
}

#define GLD16(gp, lp)                                                              \
    __builtin_amdgcn_global_load_lds(                                              \
        (__attribute__((address_space(1))) void*)(gp),                             \
        (__attribute__((address_space(3))) void*)(lp), 16, 0, 0)

// ---------------- fp32 -> bf16 bulk convert (grid = n/1024) ----------------
__global__ void __launch_bounds__(256) k_convert(const float* __restrict__ in,
                                                 unsigned short* __restrict__ out) {
    size_t i = (size_t)blockIdx.x * 256 + threadIdx.x;
    float4 f = ((const float4*)in)[i];
    ushort4v o = { f2bf(f.x), f2bf(f.y), f2bf(f.z), f2bf(f.w) };
    ((ushort4v*)out)[i] = o;
}

// ---------------- RoPE table: tab[pos*64+i], i<32 -> sin, i>=32 -> cos ----------------
__global__ void __launch_bounds__(256) k_rope(float* __restrict__ tab) {
    int g = blockIdx.x * 256 + threadIdx.x;   // 0..262143
    int pos = g >> 6, i = g & 63, j = i & 31;
    float freq = expf(-(float)j * (logf(10000.0f) / 31.0f));
    float ang  = (float)pos * freq;
    tab[g] = (i < 32) ? sinf(ang) : cosf(ang);
}

// ---------------- router scores: one wave per row ----------------
__global__ void __launch_bounds__(256) k_router(const float* __restrict__ q,
                                                const float* __restrict__ wv,
                                                float* __restrict__ rw) {
    int row  = blockIdx.x * 4 + (threadIdx.x >> 6);
    int lane = threadIdx.x & 63;
    const float* p  = q  + (size_t)row * DM + lane * 16;
    const float* wp = wv + lane * 16;
    float s = 0.f;
#pragma unroll
    for (int j = 0; j < 4; j++) {
        float4 a = ((const float4*)p)[j];
        float4 b = ((const float4*)wp)[j];
        s += a.x * b.x + a.y * b.y + a.z * b.z + a.w * b.w;
    }
#pragma unroll
    for (int m = 32; m > 0; m >>= 1) s += __shfl_xor(s, m, 64);
    if (lane == 0) rw[row] = s;
}

// ---------------- top-512 of 4096 via bitonic sort on (value desc, idx asc) ----------------
__global__ void __launch_bounds__(1024) k_topk(const float* __restrict__ rw,
                                               int* __restrict__ sel,
                                               float* __restrict__ selw) {
    __shared__ unsigned long long keys[4096];
    int b = blockIdx.x, t = threadIdx.x;
    for (int i = t; i < 4096; i += 1024) {
        float v = rw[b * 4096 + i];
        unsigned u = __float_as_uint(v);
        u = (u & 0x80000000u) ? ~u : (u | 0x80000000u);    // monotonic ascending transform
        keys[i] = ((unsigned long long)(~u) << 32) | (unsigned)i;  // ascending key = value desc, idx asc
    }
    __syncthreads();
    for (int k = 2; k <= 4096; k <<= 1)
        for (int j = k >> 1; j > 0; j >>= 1) {
            for (int i = t; i < 4096; i += 1024) {
                int ixj = i ^ j;
                if (ixj > i) {
                    bool up = ((i & k) == 0);
                    unsigned long long a = keys[i], c = keys[ixj];
                    if ((a > c) == up) { keys[i] = c; keys[ixj] = a; }
                }
            }
            __syncthreads();
        }
    for (int i = t; i < 512; i += 1024) {
        unsigned idx = (unsigned)(keys[i] & 0xFFFFFFFFu);
        sel[b * 512 + i]  = (int)idx;
        selw[b * 512 + i] = rw[b * 4096 + idx];
    }
}

// ---------------- gather selected query rows -> bf16 ----------------
__global__ void __launch_bounds__(256) k_gather(const float* __restrict__ q,
                                                const int* __restrict__ sel,
                                                unsigned short* __restrict__ out) {
    int row = blockIdx.x;                  // b*512 + c
    int b = row >> 9;
    int s = sel[row];
    const float4* src = (const float4*)(q + ((size_t)b * SQ + s) * DM);
    ushort4v* dst = (ushort4v*)(out + (size_t)row * DM);
    float4 f = src[threadIdx.x];
    ushort4v o = { f2bf(f.x), f2bf(f.y), f2bf(f.z), f2bf(f.w) };
    dst[threadIdx.x] = o;
}

// ---------------- 128xBNx32 MFMA GEMM, C = A * Bw^T, swizzled LDS, fused epilogues -------
// LDS chunk swizzle: global chunk (row, kc) -> slot row*4 + ((kc + (row>>1)) & 3).
// Makes b128 fragment reads hit all 8 bank groups 2x (2-way = free) despite the
// lane-contiguous LDS layout forced by global_load_lds.
// MODE 0: kv projection -> k_attn (B,H,S,d) with RoPE, v_attn transposed (B,H,d,S)
// MODE 1: q projection  -> q_attn (B,H,C,d) with RoPE(sel pos) * 0.125*log2e
// MODE 2: out projection -> scatter fp32 rows * selw into out
template <int MODE, int BN>
__global__ void __launch_bounds__(256) k_gemm(
    const unsigned short* __restrict__ A,
    const unsigned short* __restrict__ Bw,
    int M, int N, int K,
    const float* __restrict__ rope_tab,
    const int* __restrict__ sel,
    const float* __restrict__ selw,
    unsigned short* __restrict__ ok,
    unsigned short* __restrict__ ov,
    unsigned short* __restrict__ obf,
    float* __restrict__ of) {
    constexpr int TN = BN / 32;                 // N-frags per wave
    __shared__ unsigned short lA[128 * 32];
    __shared__ unsigned short lB[BN * 32];
    const int tid = threadIdx.x;
    const int w = tid >> 6, lane = tid & 63, quad = lane >> 4, l16 = lane & 15;
    const int wr = w >> 1, wc = w & 1;
    const int mBase = blockIdx.y * 128, nBase = blockIdx.x * BN;

    f32x4 acc[4][TN] = {};

    for (int k0 = 0; k0 < K; k0 += 32) {
#pragma unroll
        for (int is = 0; is < 2; is++) {        // A: 512 chunks of 16B
            int slot = is * 256 + tid;
            int row = slot >> 2, sc = slot & 3;
            int kc = (sc - (row >> 1)) & 3;
            const char* ga = (const char*)A + (((size_t)(mBase + row) * K) + k0 + kc * 8) * 2;
            GLD16(ga, (char*)lA + slot * 16);
        }
#pragma unroll
        for (int is = 0; is < BN / 64; is++) {  // B: BN*4 chunks
            int slot = is * 256 + tid;
            int row = slot >> 2, sc = slot & 3;
            int kc = (sc - (row >> 1)) & 3;
            const char* gb = (const char*)Bw + (((size_t)(nBase + row) * K) + k0 + kc * 8) * 2;
            GLD16(gb, (char*)lB + slot * 16);
        }
        __syncthreads();
        short8 af[4], bfr[TN];
#pragma unroll
        for (int t = 0; t < 4; t++) {
            int r = wr * 64 + t * 16 + l16;
            af[t] = *(const short8*)&lA[r * 32 + (((quad + (r >> 1)) & 3) * 8)];
        }
#pragma unroll
        for (int t = 0; t < TN; t++) {
            int r = wc * (BN / 2) + t * 16 + l16;
            bfr[t] = *(const short8*)&lB[r * 32 + (((quad + (r >> 1)) & 3) * 8)];
        }
#pragma unroll
        for (int tm = 0; tm < 4; tm++)
#pragma unroll
            for (int tn = 0; tn < TN; tn++)
                acc[tm][tn] = mfma_bf16(af[tm], bfr[tn], acc[tm][tn]);
        __syncthreads();
    }

#pragma unroll
    for (int tm = 0; tm < 4; tm++) {
#pragma unroll
        for (int tn = 0; tn < TN; tn++) {
#pragma unroll
            for (int r = 0; r < 4; r++) {
                int m = mBase + wr * 64 + tm * 16 + quad * 4 + r;
                int n = nBase + wc * (BN / 2) + tn * 16 + l16;
                float v = acc[tm][tn][r];
                if constexpr (MODE == 0) {
                    int b = m >> 12, s = m & 4095;
                    if (n < 1024) {
                        int h = n >> 6, i = n & 63;
                        v *= rope_tab[(s << 6) | i];
                        ok[(((size_t)(b * NH + h) * SKV) + s) * HD + i] = f2bf(v);
                    } else {
                        int e = n - 1024, h = e >> 6, i = e & 63;
                        ov[(((size_t)(b * NH + h) * HD) + i) * SKV + s] = f2bf(v);
                    }
                } else if constexpr (MODE == 1) {
                    int b = m >> 9, c = m & 511;
                    int h = n >> 6, i = n & 63;
                    float rp = rope_tab[(sel[m] << 6) | i];
                    // 0.125/sqrt-d scale * log2(e) so attention can use native exp2
                    obf[(((size_t)(b * NH + h) * CAP) + c) * HD + i] =
                        f2bf(v * rp * 0.18033688011112042f);
                } else {
                    int b = m >> 9;
                    int s = sel[m];
                    of[(((size_t)b * SQ) + s) * DM + n] = v * selw[m];
                }
            }
        }
    }
}

// ---------------- flash attention (KV-split, no-max softmax, unnormalized partials) ------
// grid (CAP/128, B*NH, ASPLIT), block 256. Each wave: 32 q-rows. Partials fp32.
__global__ void __launch_bounds__(256) k_attention(
    const unsigned short* __restrict__ Q,    // (B,H,C,d), pre-scaled by log2e/8
    const unsigned short* __restrict__ Kg,   // (B,H,S,d)
    const unsigned short* __restrict__ Vt,   // (B,H,d,S)
    float* __restrict__ Opart,               // (ASPLIT,B*H,C,d) unnormalized
    float* __restrict__ Lpart) {             // (ASPLIT,B*H,C)
    __shared__ unsigned short lK[64 * 72];       // [s][i], padded
    __shared__ unsigned short lV[64 * 72];       // [i][s], padded
    __shared__ unsigned short lP[4][32 * 72];    // per-wave P round-trip
    const int bh = blockIdx.y, z = blockIdx.z;
    const int tid = threadIdx.x, w = tid >> 6, lane = tid & 63;
    const int quad = lane >> 4, l16 = lane & 15;
    const int qb = blockIdx.x * 128 + w * 32;        // wave's q base (32 rows)
    const int base = z * KVPER;

    short8 qf[2][2];
#pragma unroll
    for (int rt = 0; rt < 2; rt++) {
        const unsigned short* qp = Q + ((size_t)bh * CAP + qb + rt * 16 + l16) * HD + quad * 8;
        qf[rt][0] = *(const short8*)qp;
        qf[rt][1] = *(const short8*)(qp + 32);
    }

    const unsigned short* kb = Kg + (size_t)bh * SKV * HD;
    const unsigned short* vb = Vt + (size_t)bh * HD * SKV;
    const int sr = tid >> 2, sp = tid & 3;           // staging: row, 16-half chunk

    f32x4 o[2][4] = {};
    f32x4 lsum[2] = {};
    short8 ones = (short8)0x3F80;                    // bf16 1.0 splat

    short8 rk0, rk1, rv0, rv1;
    {
        const short8* srck = (const short8*)(kb + (size_t)(base + sr) * HD + sp * 16);
        rk0 = srck[0]; rk1 = srck[1];
        const short8* srcv = (const short8*)(vb + (size_t)sr * SKV + base + sp * 16);
        rv0 = srcv[0]; rv1 = srcv[1];
    }

    unsigned short* lPw = &lP[w][0];

    for (int it = 0; it < AITERS; it++) {
        __syncthreads();
        *(short8*)&lK[sr * 72 + sp * 16]     = rk0;
        *(short8*)&lK[sr * 72 + sp * 16 + 8] = rk1;
        *(short8*)&lV[sr * 72 + sp * 16]     = rv0;
        *(short8*)&lV[sr * 72 + sp * 16 + 8] = rv1;
        if (it + 1 < AITERS) {
            int s0 = base + (it + 1) * 64;
            const short8* srck = (const short8*)(kb + (size_t)(s0 + sr) * HD + sp * 16);
            rk0 = srck[0]; rk1 = srck[1];
            const short8* srcv = (const short8*)(vb + (size_t)sr * SKV + s0 + sp * 16);
            rv0 = srcv[0]; rv1 = srcv[1];
        }
        __syncthreads();

        f32x4 sc[2][4] = {};
#pragma unroll
        for (int tn = 0; tn < 4; tn++) {
            short8 kf0 = *(const short8*)&lK[(tn * 16 + l16) * 72 + quad * 8];
            short8 kf1 = *(const short8*)&lK[(tn * 16 + l16) * 72 + 32 + quad * 8];
#pragma unroll
            for (int rt = 0; rt < 2; rt++) {
                sc[rt][tn] = mfma_bf16(qf[rt][0], kf0, sc[rt][tn]);
                sc[rt][tn] = mfma_bf16(qf[rt][1], kf1, sc[rt][tn]);
            }
        }
        // P = exp2(score2) — scores pre-scaled by log2e; bounded ~|4|, clamp 86 insurance
#pragma unroll
        for (int rt = 0; rt < 2; rt++)
#pragma unroll
            for (int tn = 0; tn < 4; tn++)
#pragma unroll
                for (int r = 0; r < 4; r++)
                    lPw[(rt * 16 + quad * 4 + r) * 72 + tn * 16 + l16] =
                        f2bf(exp2f(fminf(sc[rt][tn][r], 86.f)));
        // PV + row-sum via ones-MFMA (wave-private lP: no barrier needed)
#pragma unroll
        for (int kc = 0; kc < 2; kc++) {
            short8 pf0 = *(const short8*)&lPw[(l16) * 72 + kc * 32 + quad * 8];
            short8 pf1 = *(const short8*)&lPw[(16 + l16) * 72 + kc * 32 + quad * 8];
            lsum[0] = mfma_bf16(pf0, ones, lsum[0]);
            lsum[1] = mfma_bf16(pf1, ones, lsum[1]);
#pragma unroll
            for (int tn = 0; tn < 4; tn++) {
                short8 vf = *(const short8*)&lV[(tn * 16 + l16) * 72 + kc * 32 + quad * 8];
                o[0][tn] = mfma_bf16(pf0, vf, o[0][tn]);
                o[1][tn] = mfma_bf16(pf1, vf, o[1][tn]);
            }
        }
    }

    float* Ob = Opart + (((size_t)(z * 64 + bh)) * CAP + qb) * HD;
#pragma unroll
    for (int rt = 0; rt < 2; rt++)
#pragma unroll
        for (int tn = 0; tn < 4; tn++)
#pragma unroll
            for (int r = 0; r < 4; r++)
                Ob[(size_t)(rt * 16 + quad * 4 + r) * HD + tn * 16 + l16] = o[rt][tn][r];
    if (l16 == 0) {
#pragma unroll
        for (int rt = 0; rt < 2; rt++)
#pragma unroll
            for (int r = 0; r < 4; r++)
                Lpart[((size_t)(z * 64 + bh)) * CAP + qb + rt * 16 + quad * 4 + r] = lsum[rt][r];
    }
}

// ---------------- combine split partials -> att_bf (B,C,H*d) ----------------
__global__ void __launch_bounds__(256) k_combine(
    const float* __restrict__ Opart, const float* __restrict__ Lpart,
    unsigned short* __restrict__ att) {
    int g = blockIdx.x * 256 + threadIdx.x;
    int dall = g & 1023, c = (g >> 10) & 511, b = g >> 19;
    int h = dall >> 6, dd = dall & 63;
    int bh = b * NH + h;
    float os = 0.f, ls = 0.f;
#pragma unroll
    for (int p = 0; p < ASPLIT; p++) {
        os += Opart[(((size_t)(p * 64 + bh)) * CAP + c) * HD + dd];
        ls += Lpart[((size_t)(p * 64 + bh)) * CAP + c];
    }
    att[g] = f2bf(os / ls);
}

extern "C" void kernel_launch(void* const* d_in, const int* in_sizes, int n_in,
                              void* d_out, int out_size, void* d_ws, size_t ws_size,
                              hipStream_t stream) {
    const float* query    = (const float*)d_in[0];
    const float* value    = (const float*)d_in[1];
    const float* router_w = (const float*)d_in[2];
    const float* q_w      = (const float*)d_in[3];
    const float* kv_w     = (const float*)d_in[4];
    const float* out_w    = (const float*)d_in[5];
    float* out = (float*)d_out;

    char* p = (char*)d_ws;
    unsigned short* value_bf = (unsigned short*)p; p += (size_t)B_ * SKV * DM * 2;  // 33.5MB
    unsigned short* kvw_bf   = (unsigned short*)p; p += (size_t)2 * DM * DM * 2;    // 4MB
    unsigned short* qw_bf    = (unsigned short*)p; p += (size_t)DM * DM * 2;        // 2MB
    unsigned short* ow_bf    = (unsigned short*)p; p += (size_t)DM * DM * 2;        // 2MB
    unsigned short* res_bf   = (unsigned short*)p; p += (size_t)B_ * CAP * DM * 2;  // 4MB
    unsigned short* q_attn   = (unsigned short*)p; p += (size_t)B_ * CAP * DM * 2;  // 4MB
    unsigned short* kbuf     = (unsigned short*)p; p += (size_t)B_ * SKV * DM * 2;  // 33.5MB
    unsigned short* vbuf     = (unsigned short*)p; p += (size_t)B_ * SKV * DM * 2;  // 33.5MB
    unsigned short* att_bf   = (unsigned short*)p; p += (size_t)B_ * CAP * DM * 2;  // 4MB
    float* rope_tab = (float*)p; p += (size_t)SKV * HD * 4;                          // 1MB
    float* rw       = (float*)p; p += (size_t)B_ * SQ * 4;
    int*   sel      = (int*)p;   p += (size_t)B_ * CAP * 4;
    float* selw     = (float*)p; p += (size_t)B_ * CAP * 4;
    // attention partials alias buffers dead by attention time
    float* Opart = (float*)value_bf;   // 32MB <= 33.5MB
    float* Lpart = (float*)res_bf;     // 512KB <= 4MB

    hipMemsetAsync(d_out, 0, (size_t)out_size * sizeof(float), stream);

    k_convert<<<B_ * SKV * DM / 1024, 256, 0, stream>>>(value, value_bf);
    k_convert<<<2 * DM * DM / 1024, 256, 0, stream>>>(kv_w, kvw_bf);
    k_convert<<<DM * DM / 1024, 256, 0, stream>>>(q_w, qw_bf);
    k_convert<<<DM * DM / 1024, 256, 0, stream>>>(out_w, ow_bf);
    k_rope<<<SKV * HD / 256, 256, 0, stream>>>(rope_tab);
    k_router<<<B_ * SQ / 4, 256, 0, stream>>>(query, router_w, rw);
    k_topk<<<B_, 1024, 0, stream>>>(rw, sel, selw);
    k_gather<<<B_ * CAP, 256, 0, stream>>>(query, sel, res_bf);

    // kv projection + RoPE(k) + layout
    k_gemm<0, 128><<<dim3(2 * DM / 128, B_ * SKV / 128), 256, 0, stream>>>(
        value_bf, kvw_bf, B_ * SKV, 2 * DM, DM, rope_tab, nullptr, nullptr,
        kbuf, vbuf, nullptr, nullptr);
    // q projection + RoPE(sel) + (log2e)/sqrt(d)
    k_gemm<1, 64><<<dim3(DM / 64, B_ * CAP / 128), 256, 0, stream>>>(
        res_bf, qw_bf, B_ * CAP, DM, DM, rope_tab, sel, nullptr,
        nullptr, nullptr, q_attn, nullptr);

    k_attention<<<dim3(CAP / 128, B_ * NH, ASPLIT), 256, 0, stream>>>(
        q_attn, kbuf, vbuf, Opart, Lpart);
    k_combine<<<B_ * CAP * DM / 256, 256, 0, stream>>>(Opart, Lpart, att_bf);

    // out projection + topw scale + scatter
    k_gemm<2, 64><<<dim3(DM / 64, B_ * CAP / 128), 256, 0, stream>>>(
        att_bf, ow_bf, B_ * CAP, DM, DM, nullptr, sel, selw,
        nullptr, nullptr, nullptr, out);
}

// Round 4
// 489.132 us; speedup vs baseline: 1.2605x; 1.0707x over previous
//
#include <hip/hip_runtime.h>
#include <hip/hip_bf16.h>

#define B_  4
#define SQ  4096
#define SKV 4096
#define DM  1024
#define NH  16
#define HD  64
#define CAP 512

#define ASPLIT 4
#define KVPER  (SKV / ASPLIT)
#define AITERS (KVPER / 64)

typedef __attribute__((ext_vector_type(8))) short    short8;   // 8 bf16 payload (4 VGPRs)
typedef __attribute__((ext_vector_type(8))) __bf16   bf16v8;   // builtin operand type
typedef __attribute__((ext_vector_type(4))) float    f32x4;
typedef __attribute__((ext_vector_type(4))) unsigned short ushort4v;

static __device__ __forceinline__ unsigned short f2bf(float f) {
    unsigned u = __float_as_uint(f);
    u += 0x7FFFu + ((u >> 16) & 1u);           // round-to-nearest-even
    return (unsigned short)(u >> 16);
}

static __device__ __forceinline__ f32x4 mfma_bf16(short8 a, short8 b, f32x4 c) {
    return __builtin_amdgcn_mfma_f32_16x16x32_bf16(
        __builtin_bit_cast(bf16v8, a), __builtin_bit_cast(bf16v8, b), c, 0, 0, 0);
}

#define GLD16(gp, lp)                                                              \
    __builtin_amdgcn_global_load_lds(                                              \
        (__attribute__((address_space(1))) void*)(gp),                             \
        (__attribute__((address_space(3))) void*)(lp), 16, 0, 0)

// ---------------- fp32 -> bf16 bulk convert (grid = n/1024) ----------------
__global__ void __launch_bounds__(256) k_convert(const float* __restrict__ in,
                                                 unsigned short* __restrict__ out) {
    size_t i = (size_t)blockIdx.x * 256 + threadIdx.x;
    float4 f = ((const float4*)in)[i];
    ushort4v o = { f2bf(f.x), f2bf(f.y), f2bf(f.z), f2bf(f.w) };
    ((ushort4v*)out)[i] = o;
}

// ---------------- RoPE table: tab[pos*64+i], i<32 -> sin, i>=32 -> cos ----------------
__global__ void __launch_bounds__(256) k_rope(float* __restrict__ tab) {
    int g = blockIdx.x * 256 + threadIdx.x;   // 0..262143
    int pos = g >> 6, i = g & 63, j = i & 31;
    float freq = expf(-(float)j * (logf(10000.0f) / 31.0f));
    float ang  = (float)pos * freq;
    tab[g] = (i < 32) ? sinf(ang) : cosf(ang);
}

// ---------------- router scores: one wave per row ----------------
__global__ void __launch_bounds__(256) k_router(const float* __restrict__ q,
                                                const float* __restrict__ wv,
                                                float* __restrict__ rw) {
    int row  = blockIdx.x * 4 + (threadIdx.x >> 6);
    int lane = threadIdx.x & 63;
    const float* p  = q  + (size_t)row * DM + lane * 16;
    const float* wp = wv + lane * 16;
    float s = 0.f;
#pragma unroll
    for (int j = 0; j < 4; j++) {
        float4 a = ((const float4*)p)[j];
        float4 b = ((const float4*)wp)[j];
        s += a.x * b.x + a.y * b.y + a.z * b.z + a.w * b.w;
    }
#pragma unroll
    for (int m = 32; m > 0; m >>= 1) s += __shfl_xor(s, m, 64);
    if (lane == 0) rw[row] = s;
}

// ---------------- top-512 of 4096 via bitonic sort on (value desc, idx asc) ----------------
__global__ void __launch_bounds__(1024) k_topk(const float* __restrict__ rw,
                                               int* __restrict__ sel,
                                               float* __restrict__ selw) {
    __shared__ unsigned long long keys[4096];
    int b = blockIdx.x, t = threadIdx.x;
    for (int i = t; i < 4096; i += 1024) {
        float v = rw[b * 4096 + i];
        unsigned u = __float_as_uint(v);
        u = (u & 0x80000000u) ? ~u : (u | 0x80000000u);    // monotonic ascending transform
        keys[i] = ((unsigned long long)(~u) << 32) | (unsigned)i;  // ascending key = value desc, idx asc
    }
    __syncthreads();
    for (int k = 2; k <= 4096; k <<= 1)
        for (int j = k >> 1; j > 0; j >>= 1) {
            for (int i = t; i < 4096; i += 1024) {
                int ixj = i ^ j;
                if (ixj > i) {
                    bool up = ((i & k) == 0);
                    unsigned long long a = keys[i], c = keys[ixj];
                    if ((a > c) == up) { keys[i] = c; keys[ixj] = a; }
                }
            }
            __syncthreads();
        }
    for (int i = t; i < 512; i += 1024) {
        unsigned idx = (unsigned)(keys[i] & 0xFFFFFFFFu);
        sel[b * 512 + i]  = (int)idx;
        selw[b * 512 + i] = rw[b * 4096 + idx];
    }
}

// ---------------- gather selected query rows -> bf16 ----------------
__global__ void __launch_bounds__(256) k_gather(const float* __restrict__ q,
                                                const int* __restrict__ sel,
                                                unsigned short* __restrict__ out) {
    int row = blockIdx.x;                  // b*512 + c
    int b = row >> 9;
    int s = sel[row];
    const float4* src = (const float4*)(q + ((size_t)b * SQ + s) * DM);
    ushort4v* dst = (ushort4v*)(out + (size_t)row * DM);
    float4 f = src[threadIdx.x];
    ushort4v o = { f2bf(f.x), f2bf(f.y), f2bf(f.z), f2bf(f.w) };
    dst[threadIdx.x] = o;
}

// ---------------- 128xBNx32 MFMA GEMM, C = A * Bw^T, swizzled LDS, fused epilogues -------
// LDS chunk swizzle: global chunk (row, kc) -> slot row*4 + ((kc + (row>>1)) & 3)  (R3: 0 conflicts).
// MODE 0: K projection -> kbuf (B,H,S,d) with RoPE          [normal orientation]
// MODE 3: V projection -> vbuf (B,H,d,S)                    [SWAPPED mfma operands:
//         acc row = n (h,i), col = m (s) -> transposed store is lane-coalesced]
// MODE 1: q projection  -> q_attn (B,H,C,d) with RoPE(sel pos) * 0.125*log2e
// MODE 2: out projection -> scatter fp32 rows * selw into out
template <int MODE, int BN>
__global__ void __launch_bounds__(256) k_gemm(
    const unsigned short* __restrict__ A,
    const unsigned short* __restrict__ Bw,
    int M, int N, int K,
    const float* __restrict__ rope_tab,
    const int* __restrict__ sel,
    const float* __restrict__ selw,
    unsigned short* __restrict__ ok,
    unsigned short* __restrict__ ov,
    unsigned short* __restrict__ obf,
    float* __restrict__ of) {
    constexpr int TN = BN / 32;                 // N-frags per wave
    __shared__ unsigned short lA[128 * 32];
    __shared__ unsigned short lB[BN * 32];
    const int tid = threadIdx.x;
    const int w = tid >> 6, lane = tid & 63, quad = lane >> 4, l16 = lane & 15;
    const int wr = w >> 1, wc = w & 1;
    const int mBase = blockIdx.y * 128;
    const int nBase = blockIdx.x * BN + (MODE == 3 ? 1024 : 0);

    f32x4 acc[4][TN] = {};

    for (int k0 = 0; k0 < K; k0 += 32) {
#pragma unroll
        for (int is = 0; is < 2; is++) {        // A: 512 chunks of 16B
            int slot = is * 256 + tid;
            int row = slot >> 2, sc = slot & 3;
            int kc = (sc - (row >> 1)) & 3;
            const char* ga = (const char*)A + (((size_t)(mBase + row) * K) + k0 + kc * 8) * 2;
            GLD16(ga, (char*)lA + slot * 16);
        }
#pragma unroll
        for (int is = 0; is < BN / 64; is++) {  // B: BN*4 chunks
            int slot = is * 256 + tid;
            int row = slot >> 2, sc = slot & 3;
            int kc = (sc - (row >> 1)) & 3;
            const char* gb = (const char*)Bw + (((size_t)(nBase + row) * K) + k0 + kc * 8) * 2;
            GLD16(gb, (char*)lB + slot * 16);
        }
        __syncthreads();
        short8 af[4], bfr[TN];
#pragma unroll
        for (int t = 0; t < 4; t++) {
            int r = wr * 64 + t * 16 + l16;
            af[t] = *(const short8*)&lA[r * 32 + (((quad + (r >> 1)) & 3) * 8)];
        }
#pragma unroll
        for (int t = 0; t < TN; t++) {
            int r = wc * (BN / 2) + t * 16 + l16;
            bfr[t] = *(const short8*)&lB[r * 32 + (((quad + (r >> 1)) & 3) * 8)];
        }
#pragma unroll
        for (int tm = 0; tm < 4; tm++)
#pragma unroll
            for (int tn = 0; tn < TN; tn++) {
                if constexpr (MODE == 3)
                    acc[tm][tn] = mfma_bf16(bfr[tn], af[tm], acc[tm][tn]);  // C[n][m]
                else
                    acc[tm][tn] = mfma_bf16(af[tm], bfr[tn], acc[tm][tn]);  // C[m][n]
            }
        __syncthreads();
    }

#pragma unroll
    for (int tm = 0; tm < 4; tm++) {
#pragma unroll
        for (int tn = 0; tn < TN; tn++) {
#pragma unroll
            for (int r = 0; r < 4; r++) {
                float v = acc[tm][tn][r];
                if constexpr (MODE == 3) {
                    // swapped: row index -> n, col (l16) -> m
                    int n = nBase + wc * (BN / 2) + tn * 16 + quad * 4 + r;
                    int m = mBase + wr * 64 + tm * 16 + l16;
                    int e = n - 1024, h = e >> 6, i = e & 63;
                    int b = m >> 12, s = m & 4095;
                    ov[(((size_t)(b * NH + h) * HD) + i) * SKV + s] = f2bf(v);
                } else {
                    int m = mBase + wr * 64 + tm * 16 + quad * 4 + r;
                    int n = nBase + wc * (BN / 2) + tn * 16 + l16;
                    if constexpr (MODE == 0) {
                        int b = m >> 12, s = m & 4095;
                        int h = n >> 6, i = n & 63;
                        v *= rope_tab[(s << 6) | i];
                        ok[(((size_t)(b * NH + h) * SKV) + s) * HD + i] = f2bf(v);
                    } else if constexpr (MODE == 1) {
                        int b = m >> 9, c = m & 511;
                        int h = n >> 6, i = n & 63;
                        float rp = rope_tab[(sel[m] << 6) | i];
                        // 0.125/sqrt-d scale * log2(e) so attention can use native exp2
                        obf[(((size_t)(b * NH + h) * CAP) + c) * HD + i] =
                            f2bf(v * rp * 0.18033688011112042f);
                    } else {
                        int b = m >> 9;
                        int s = sel[m];
                        of[(((size_t)b * SQ) + s) * DM + n] = v * selw[m];
                    }
                }
            }
        }
    }
}

// ---------------- flash attention (KV-split, no-max softmax, unnormalized partials) ------
// grid (CAP/128, B*NH, ASPLIT), block 256. Each wave: 32 q-rows. Partials fp32.
__global__ void __launch_bounds__(256) k_attention(
    const unsigned short* __restrict__ Q,    // (B,H,C,d), pre-scaled by log2e/8
    const unsigned short* __restrict__ Kg,   // (B,H,S,d)
    const unsigned short* __restrict__ Vt,   // (B,H,d,S)
    float* __restrict__ Opart,               // (ASPLIT,B*H,C,d) unnormalized
    float* __restrict__ Lpart) {             // (ASPLIT,B*H,C)
    __shared__ unsigned short lK[64 * 72];       // [s][i], padded
    __shared__ unsigned short lV[64 * 72];       // [i][s], padded
    __shared__ unsigned short lP[4][32 * 72];    // per-wave P round-trip
    const int bh = blockIdx.y, z = blockIdx.z;
    const int tid = threadIdx.x, w = tid >> 6, lane = tid & 63;
    const int quad = lane >> 4, l16 = lane & 15;
    const int qb = blockIdx.x * 128 + w * 32;        // wave's q base (32 rows)
    const int base = z * KVPER;

    short8 qf[2][2];
#pragma unroll
    for (int rt = 0; rt < 2; rt++) {
        const unsigned short* qp = Q + ((size_t)bh * CAP + qb + rt * 16 + l16) * HD + quad * 8;
        qf[rt][0] = *(const short8*)qp;
        qf[rt][1] = *(const short8*)(qp + 32);
    }

    const unsigned short* kb = Kg + (size_t)bh * SKV * HD;
    const unsigned short* vb = Vt + (size_t)bh * HD * SKV;
    const int sr = tid >> 2, sp = tid & 3;           // staging: row, 16-half chunk

    f32x4 o[2][4] = {};
    f32x4 lsum[2] = {};
    short8 ones = (short8)0x3F80;                    // bf16 1.0 splat

    short8 rk0, rk1, rv0, rv1;
    {
        const short8* srck = (const short8*)(kb + (size_t)(base + sr) * HD + sp * 16);
        rk0 = srck[0]; rk1 = srck[1];
        const short8* srcv = (const short8*)(vb + (size_t)sr * SKV + base + sp * 16);
        rv0 = srcv[0]; rv1 = srcv[1];
    }

    unsigned short* lPw = &lP[w][0];

    for (int it = 0; it < AITERS; it++) {
        __syncthreads();
        *(short8*)&lK[sr * 72 + sp * 16]     = rk0;
        *(short8*)&lK[sr * 72 + sp * 16 + 8] = rk1;
        *(short8*)&lV[sr * 72 + sp * 16]     = rv0;
        *(short8*)&lV[sr * 72 + sp * 16 + 8] = rv1;
        if (it + 1 < AITERS) {
            int s0 = base + (it + 1) * 64;
            const short8* srck = (const short8*)(kb + (size_t)(s0 + sr) * HD + sp * 16);
            rk0 = srck[0]; rk1 = srck[1];
            const short8* srcv = (const short8*)(vb + (size_t)sr * SKV + s0 + sp * 16);
            rv0 = srcv[0]; rv1 = srcv[1];
        }
        __syncthreads();

        f32x4 sc[2][4] = {};
#pragma unroll
        for (int tn = 0; tn < 4; tn++) {
            short8 kf0 = *(const short8*)&lK[(tn * 16 + l16) * 72 + quad * 8];
            short8 kf1 = *(const short8*)&lK[(tn * 16 + l16) * 72 + 32 + quad * 8];
#pragma unroll
            for (int rt = 0; rt < 2; rt++) {
                sc[rt][tn] = mfma_bf16(qf[rt][0], kf0, sc[rt][tn]);
                sc[rt][tn] = mfma_bf16(qf[rt][1], kf1, sc[rt][tn]);
            }
        }
        // P = exp2(score2) — scores pre-scaled by log2e; bounded ~|4|, clamp 86 insurance
#pragma unroll
        for (int rt = 0; rt < 2; rt++)
#pragma unroll
            for (int tn = 0; tn < 4; tn++)
#pragma unroll
                for (int r = 0; r < 4; r++)
                    lPw[(rt * 16 + quad * 4 + r) * 72 + tn * 16 + l16] =
                        f2bf(exp2f(fminf(sc[rt][tn][r], 86.f)));
        // PV + row-sum via ones-MFMA (wave-private lP: no barrier needed)
#pragma unroll
        for (int kc = 0; kc < 2; kc++) {
            short8 pf0 = *(const short8*)&lPw[(l16) * 72 + kc * 32 + quad * 8];
            short8 pf1 = *(const short8*)&lPw[(16 + l16) * 72 + kc * 32 + quad * 8];
            lsum[0] = mfma_bf16(pf0, ones, lsum[0]);
            lsum[1] = mfma_bf16(pf1, ones, lsum[1]);
#pragma unroll
            for (int tn = 0; tn < 4; tn++) {
                short8 vf = *(const short8*)&lV[(tn * 16 + l16) * 72 + kc * 32 + quad * 8];
                o[0][tn] = mfma_bf16(pf0, vf, o[0][tn]);
                o[1][tn] = mfma_bf16(pf1, vf, o[1][tn]);
            }
        }
    }

    float* Ob = Opart + (((size_t)(z * 64 + bh)) * CAP + qb) * HD;
#pragma unroll
    for (int rt = 0; rt < 2; rt++)
#pragma unroll
        for (int tn = 0; tn < 4; tn++)
#pragma unroll
            for (int r = 0; r < 4; r++)
                Ob[(size_t)(rt * 16 + quad * 4 + r) * HD + tn * 16 + l16] = o[rt][tn][r];
    if (l16 == 0) {
#pragma unroll
        for (int rt = 0; rt < 2; rt++)
#pragma unroll
            for (int r = 0; r < 4; r++)
                Lpart[((size_t)(z * 64 + bh)) * CAP + qb + rt * 16 + quad * 4 + r] = lsum[rt][r];
    }
}

// ---------------- combine split partials -> att_bf (B,C,H*d) ----------------
__global__ void __launch_bounds__(256) k_combine(
    const float* __restrict__ Opart, const float* __restrict__ Lpart,
    unsigned short* __restrict__ att) {
    int g = blockIdx.x * 256 + threadIdx.x;
    int dall = g & 1023, c = (g >> 10) & 511, b = g >> 19;
    int h = dall >> 6, dd = dall & 63;
    int bh = b * NH + h;
    float os = 0.f, ls = 0.f;
#pragma unroll
    for (int p = 0; p < ASPLIT; p++) {
        os += Opart[(((size_t)(p * 64 + bh)) * CAP + c) * HD + dd];
        ls += Lpart[((size_t)(p * 64 + bh)) * CAP + c];
    }
    att[g] = f2bf(os / ls);
}

extern "C" void kernel_launch(void* const* d_in, const int* in_sizes, int n_in,
                              void* d_out, int out_size, void* d_ws, size_t ws_size,
                              hipStream_t stream) {
    const float* query    = (const float*)d_in[0];
    const float* value    = (const float*)d_in[1];
    const float* router_w = (const float*)d_in[2];
    const float* q_w      = (const float*)d_in[3];
    const float* kv_w     = (const float*)d_in[4];
    const float* out_w    = (const float*)d_in[5];
    float* out = (float*)d_out;

    char* p = (char*)d_ws;
    unsigned short* value_bf = (unsigned short*)p; p += (size_t)B_ * SKV * DM * 2;  // 33.5MB
    unsigned short* kvw_bf   = (unsigned short*)p; p += (size_t)2 * DM * DM * 2;    // 4MB
    unsigned short* qw_bf    = (unsigned short*)p; p += (size_t)DM * DM * 2;        // 2MB
    unsigned short* ow_bf    = (unsigned short*)p; p += (size_t)DM * DM * 2;        // 2MB
    unsigned short* res_bf   = (unsigned short*)p; p += (size_t)B_ * CAP * DM * 2;  // 4MB
    unsigned short* q_attn   = (unsigned short*)p; p += (size_t)B_ * CAP * DM * 2;  // 4MB
    unsigned short* kbuf     = (unsigned short*)p; p += (size_t)B_ * SKV * DM * 2;  // 33.5MB
    unsigned short* vbuf     = (unsigned short*)p; p += (size_t)B_ * SKV * DM * 2;  // 33.5MB
    unsigned short* att_bf   = (unsigned short*)p; p += (size_t)B_ * CAP * DM * 2;  // 4MB
    float* rope_tab = (float*)p; p += (size_t)SKV * HD * 4;                          // 1MB
    float* rw       = (float*)p; p += (size_t)B_ * SQ * 4;
    int*   sel      = (int*)p;   p += (size_t)B_ * CAP * 4;
    float* selw     = (float*)p; p += (size_t)B_ * CAP * 4;
    // attention partials alias buffers dead by attention time
    float* Opart = (float*)value_bf;   // 32MB <= 33.5MB
    float* Lpart = (float*)res_bf;     // 512KB <= 4MB

    hipMemsetAsync(d_out, 0, (size_t)out_size * sizeof(float), stream);

    k_convert<<<B_ * SKV * DM / 1024, 256, 0, stream>>>(value, value_bf);
    k_convert<<<2 * DM * DM / 1024, 256, 0, stream>>>(kv_w, kvw_bf);
    k_convert<<<DM * DM / 1024, 256, 0, stream>>>(q_w, qw_bf);
    k_convert<<<DM * DM / 1024, 256, 0, stream>>>(out_w, ow_bf);
    k_rope<<<SKV * HD / 256, 256, 0, stream>>>(rope_tab);
    k_router<<<B_ * SQ / 4, 256, 0, stream>>>(query, router_w, rw);
    k_topk<<<B_, 1024, 0, stream>>>(rw, sel, selw);
    k_gather<<<B_ * CAP, 256, 0, stream>>>(query, sel, res_bf);

    // K projection + RoPE(k)  (columns 0..1023 of kv_w)
    k_gemm<0, 128><<<dim3(DM / 128, B_ * SKV / 128), 256, 0, stream>>>(
        value_bf, kvw_bf, B_ * SKV, DM, DM, rope_tab, nullptr, nullptr,
        kbuf, nullptr, nullptr, nullptr);
    // V projection, swapped-operand transposed store (columns 1024..2047)
    k_gemm<3, 128><<<dim3(DM / 128, B_ * SKV / 128), 256, 0, stream>>>(
        value_bf, kvw_bf, B_ * SKV, DM, DM, nullptr, nullptr, nullptr,
        nullptr, vbuf, nullptr, nullptr);
    // q projection + RoPE(sel) + (log2e)/sqrt(d)
    k_gemm<1, 64><<<dim3(DM / 64, B_ * CAP / 128), 256, 0, stream>>>(
        res_bf, qw_bf, B_ * CAP, DM, DM, rope_tab, sel, nullptr,
        nullptr, nullptr, q_attn, nullptr);

    k_attention<<<dim3(CAP / 128, B_ * NH, ASPLIT), 256, 0, stream>>>(
        q_attn, kbuf, vbuf, Opart, Lpart);
    k_combine<<<B_ * CAP * DM / 256, 256, 0, stream>>>(Opart, Lpart, att_bf);

    // out projection + topw scale + scatter
    k_gemm<2, 64><<<dim3(DM / 64, B_ * CAP / 128), 256, 0, stream>>>(
        att_bf, ow_bf, B_ * CAP, DM, DM, nullptr, sel, selw,
        nullptr, nullptr, nullptr, out);
}